// Round 1
// baseline (4978.580 us; speedup 1.0000x reference)
//
#include <hip/hip_runtime.h>

#define NFEAT 64
#define NCAT 192

__global__ void deg_kernel(const int* __restrict__ dst, float* __restrict__ degf, int nedges) {
    int e = blockIdx.x * blockDim.x + threadIdx.x;
    if (e < nedges) atomicAdd(&degf[dst[e]], 1.0f);
}

__global__ void cnt_kernel(const int* __restrict__ batch, float* __restrict__ cnt, int n) {
    int i = blockIdx.x * blockDim.x + threadIdx.x;
    if (i < n) atomicAdd(&cnt[batch[i]], 1.0f);
}

__global__ void recip_kernel(float* __restrict__ degf, int n) {
    int i = blockIdx.x * blockDim.x + threadIdx.x;
    if (i < n) degf[i] = 1.0f / fmaxf(degf[i], 1.0f);
}

// One edge handled by 16 consecutive threads; each thread moves 4 contiguous floats.
__global__ void scatter_kernel(const float* __restrict__ xin, const int* __restrict__ src,
                               const int* __restrict__ dst, float* __restrict__ agg, int nedges) {
    int tid = blockIdx.x * blockDim.x + threadIdx.x;
    int e = tid >> 4;
    if (e >= nedges) return;
    int c = (tid & 15) << 2;
    int s = src[e], d = dst[e];
    const float4 v = *reinterpret_cast<const float4*>(xin + (size_t)s * NFEAT + c);
    float* p = agg + (size_t)d * NFEAT + c;
    atomicAdd(p + 0, v.x);
    atomicAdd(p + 1, v.y);
    atomicAdd(p + 2, v.z);
    atomicAdd(p + 3, v.w);
}

// One wave per node (grid-stride). lane j computes output feature j.
// Weights staged transposed in LDS: wT[k*64+j] = W[j*64+k] -> conflict-free lane reads.
// Also accumulates per-feature sum / sumsq for BatchNorm into stats[0:64]/stats[64:128].
__global__ __launch_bounds__(256) void lin_kernel(
    const float* __restrict__ agg, const float* __restrict__ xin,
    const float* __restrict__ recip,
    const float* __restrict__ Wl, const float* __restrict__ bl,
    const float* __restrict__ Wr,
    float* __restrict__ h, float* __restrict__ stats, int n) {
    __shared__ float wlT[64 * 64];
    __shared__ float wrT[64 * 64];
    __shared__ float red1[256];
    __shared__ float red2[256];

    for (int t = threadIdx.x; t < 64 * 64; t += blockDim.x) {
        int j = t >> 6, k = t & 63;
        wlT[k * 64 + j] = Wl[t];
        wrT[k * 64 + j] = Wr[t];
    }
    __syncthreads();

    int wave = threadIdx.x >> 6;
    int lane = threadIdx.x & 63;
    int waves_per_block = blockDim.x >> 6;
    int gwave = blockIdx.x * waves_per_block + wave;
    int nwaves = gridDim.x * waves_per_block;

    float blj = bl[lane];
    float s1 = 0.0f, s2 = 0.0f;

    for (int i = gwave; i < n; i += nwaves) {
        float av = agg[(size_t)i * NFEAT + lane] * recip[i];
        float xv = xin[(size_t)i * NFEAT + lane];
        float acc = blj;
#pragma unroll
        for (int k = 0; k < 64; ++k) {
            float ak = __shfl(av, k);
            float xk = __shfl(xv, k);
            acc += ak * wlT[k * 64 + lane] + xk * wrT[k * 64 + lane];
        }
        h[(size_t)i * NFEAT + lane] = acc;
        s1 += acc;
        s2 += acc * acc;
    }

    red1[wave * 64 + lane] = s1;
    red2[wave * 64 + lane] = s2;
    __syncthreads();
    if (wave == 0) {
        float t1 = red1[lane] + red1[64 + lane] + red1[128 + lane] + red1[192 + lane];
        float t2 = red2[lane] + red2[64 + lane] + red2[128 + lane] + red2[192 + lane];
        atomicAdd(&stats[lane], t1);
        atomicAdd(&stats[64 + lane], t2);
    }
}

// BatchNorm (training stats from `stats`) + ReLU, in place on h; also accumulate
// pooled sums into pool[batch[i]*192 + colbase + j].
__global__ void bn_kernel(float* __restrict__ h, const float* __restrict__ stats,
                          const float* __restrict__ g, const float* __restrict__ b,
                          const int* __restrict__ batch, float* __restrict__ pool,
                          int colbase, int n) {
    int tid = blockIdx.x * blockDim.x + threadIdx.x;
    if (tid >= n * NFEAT) return;
    int i = tid >> 6;
    int j = tid & 63;
    float invn = 1.0f / (float)n;
    float mu = stats[j] * invn;
    float var = stats[64 + j] * invn - mu * mu;
    float sc = rsqrtf(var + 1e-5f);
    float v = (h[tid] - mu) * sc * g[j] + b[j];
    v = fmaxf(v, 0.0f);
    h[tid] = v;
    atomicAdd(&pool[(size_t)batch[i] * NCAT + colbase + j], v);
}

__global__ void final_kernel(const float* __restrict__ pool, const float* __restrict__ cnt,
                             float* __restrict__ out, int total) {
    int t = blockIdx.x * blockDim.x + threadIdx.x;
    if (t >= total) return;
    int gidx = t / NCAT;
    out[t] = pool[t] / fmaxf(cnt[gidx], 1.0f);
}

extern "C" void kernel_launch(void* const* d_in, const int* in_sizes, int n_in,
                              void* d_out, int out_size, void* d_ws, size_t ws_size,
                              hipStream_t stream) {
    const float* x = (const float*)d_in[0];
    const int* ei = (const int*)d_in[1];
    const int* batch = (const int*)d_in[2];

    const float* Wl[3], *bl[3], *Wr[3], *gm[3], *bt[3];
    for (int L = 0; L < 3; ++L) {
        Wl[L] = (const float*)d_in[3 + 5 * L + 0];
        bl[L] = (const float*)d_in[3 + 5 * L + 1];
        Wr[L] = (const float*)d_in[3 + 5 * L + 2];
        gm[L] = (const float*)d_in[3 + 5 * L + 3];
        bt[L] = (const float*)d_in[3 + 5 * L + 4];
    }

    const int n = in_sizes[0] / NFEAT;
    const int ne = in_sizes[1] / 2;
    const int ngraphs = out_size / NCAT;
    const int* src = ei;
    const int* dstp = ei + ne;

    float* ws = (float*)d_ws;
    size_t off = 0;
    float* agg = ws + off;   off += (size_t)n * NFEAT;
    float* bufA = ws + off;  off += (size_t)n * NFEAT;
    float* bufB = ws + off;  off += (size_t)n * NFEAT;
    float* degf = ws + off;  off += (size_t)n;
    float* stats = ws + off; off += 128;
    float* pool = ws + off;  off += (size_t)ngraphs * NCAT;
    float* cntf = ws + off;  off += (size_t)ngraphs;

    hipMemsetAsync(degf, 0, (size_t)n * sizeof(float), stream);
    hipMemsetAsync(cntf, 0, (size_t)ngraphs * sizeof(float), stream);
    hipMemsetAsync(pool, 0, (size_t)ngraphs * NCAT * sizeof(float), stream);

    deg_kernel<<<(ne + 255) / 256, 256, 0, stream>>>(dstp, degf, ne);
    cnt_kernel<<<(n + 255) / 256, 256, 0, stream>>>(batch, cntf, n);
    recip_kernel<<<(n + 255) / 256, 256, 0, stream>>>(degf, n);

    const float* lin_in = x;
    float* lout[3] = {bufA, bufB, bufA};
    for (int L = 0; L < 3; ++L) {
        float* dbuf = lout[L];
        hipMemsetAsync(agg, 0, (size_t)n * NFEAT * sizeof(float), stream);
        hipMemsetAsync(stats, 0, 128 * sizeof(float), stream);
        long long sthreads = (long long)ne * 16;
        scatter_kernel<<<(int)((sthreads + 255) / 256), 256, 0, stream>>>(lin_in, src, dstp, agg, ne);
        lin_kernel<<<2048, 256, 0, stream>>>(agg, lin_in, degf, Wl[L], bl[L], Wr[L], dbuf, stats, n);
        long long bthreads = (long long)n * NFEAT;
        bn_kernel<<<(int)((bthreads + 255) / 256), 256, 0, stream>>>(dbuf, stats, gm[L], bt[L], batch, pool, L * NFEAT, n);
        lin_in = dbuf;
    }
    final_kernel<<<(out_size + 255) / 256, 256, 0, stream>>>(pool, cntf, (float*)d_out, out_size);
}

// Round 2
// 1767.645 us; speedup vs baseline: 2.8165x; 2.8165x over previous
//
#include <hip/hip_runtime.h>

#define NFEAT 64
#define NCAT 192
#define BN_NODES 32
#define BN_SPAN 8

__global__ void deg_kernel(const int* __restrict__ dst, int* __restrict__ deg, int nedges) {
    int e = blockIdx.x * blockDim.x + threadIdx.x;
    if (e < nedges) atomicAdd(&deg[dst[e]], 1);
}

__global__ void cnt_kernel(const int* __restrict__ batch, float* __restrict__ cnt, int n) {
    int i = blockIdx.x * blockDim.x + threadIdx.x;
    if (i < n) atomicAdd(&cnt[batch[i]], 1.0f);
}

__global__ void recip_kernel(const int* __restrict__ deg, float* __restrict__ recip, int n) {
    int i = blockIdx.x * blockDim.x + threadIdx.x;
    if (i < n) recip[i] = 1.0f / (float)max(deg[i], 1);
}

// Single-block exclusive scan over deg -> row_start (and cursor copy).
// Wave-level shfl scan + cross-wave LDS scan, chunks of 1024.
__global__ __launch_bounds__(1024) void scan_kernel(const int* __restrict__ deg,
                                                    int* __restrict__ row_start,
                                                    int* __restrict__ cursor, int n) {
    __shared__ int wtot[16];
    __shared__ int woff[16];
    __shared__ int carry_s;
    int tid = threadIdx.x, lane = tid & 63, wid = tid >> 6;
    if (tid == 0) carry_s = 0;
    __syncthreads();
    for (int base = 0; base < n; base += 1024) {
        int i = base + tid;
        int v = (i < n) ? deg[i] : 0;
        int incl = v;
#pragma unroll
        for (int off = 1; off < 64; off <<= 1) {
            int t = __shfl_up(incl, off);
            if (lane >= off) incl += t;
        }
        if (lane == 63) wtot[wid] = incl;
        __syncthreads();
        if (wid == 0) {
            int wv = (lane < 16) ? wtot[lane] : 0;
            int winc = wv;
#pragma unroll
            for (int off = 1; off < 16; off <<= 1) {
                int t = __shfl_up(winc, off);
                if (lane >= off) winc += t;
            }
            if (lane < 16) woff[lane] = winc - wv;
        }
        __syncthreads();
        int carry = carry_s;
        int excl = carry + woff[wid] + (incl - v);
        if (i < n) { row_start[i] = excl; cursor[i] = excl; }
        int ctot = woff[15] + wtot[15];
        __syncthreads();
        if (tid == 0) carry_s = carry + ctot;
        __syncthreads();
    }
}

__global__ void fill_kernel(const int* __restrict__ src, const int* __restrict__ dst,
                            int* __restrict__ cursor, int* __restrict__ csr_src, int ne) {
    int e = blockIdx.x * blockDim.x + threadIdx.x;
    if (e < ne) {
        int d = dst[e];
        int pos = atomicAdd(&cursor[d], 1);
        csr_src[pos] = src[e];
    }
}

// Fused: per-node gather of neighbor rows (CSR, no atomics) + mean + dual matmul
// (shuffle-broadcast form, transposed weights in LDS) + BN stats accumulation.
__global__ __launch_bounds__(256) void gatherlin_kernel(
    const float* __restrict__ xin, const int* __restrict__ row_start,
    const int* __restrict__ deg, const float* __restrict__ recip,
    const int* __restrict__ csr_src,
    const float* __restrict__ Wl, const float* __restrict__ bl,
    const float* __restrict__ Wr,
    float* __restrict__ h, float* __restrict__ stats, int n) {
    __shared__ float wlT[64 * 64];
    __shared__ float wrT[64 * 64];
    __shared__ float red1[256];
    __shared__ float red2[256];

    for (int t = threadIdx.x; t < 64 * 64; t += blockDim.x) {
        int j = t >> 6, k = t & 63;
        wlT[k * 64 + j] = Wl[t];
        wrT[k * 64 + j] = Wr[t];
    }
    __syncthreads();

    int wave = threadIdx.x >> 6;
    int lane = threadIdx.x & 63;
    int waves_per_block = blockDim.x >> 6;
    int gwave = blockIdx.x * waves_per_block + wave;
    int nwaves = gridDim.x * waves_per_block;

    float blj = bl[lane];
    float s1 = 0.0f, s2 = 0.0f;

    for (int i = gwave; i < n; i += nwaves) {
        int rs = row_start[i];
        int dg = deg[i];
        float av = 0.0f;
        for (int base = 0; base < dg; base += 64) {
            int cnt = min(dg - base, 64);
            int myidx = (lane < cnt) ? csr_src[rs + base + lane] : 0;
            for (int k = 0; k < cnt; ++k) {
                int s = __shfl(myidx, k);
                av += xin[(size_t)s * NFEAT + lane];
            }
        }
        av *= recip[i];
        float xv = xin[(size_t)i * NFEAT + lane];
        float acc = blj;
#pragma unroll
        for (int k = 0; k < 64; ++k) {
            float ak = __shfl(av, k);
            float xk = __shfl(xv, k);
            acc += ak * wlT[k * 64 + lane] + xk * wrT[k * 64 + lane];
        }
        h[(size_t)i * NFEAT + lane] = acc;
        s1 += acc;
        s2 += acc * acc;
    }

    red1[wave * 64 + lane] = s1;
    red2[wave * 64 + lane] = s2;
    __syncthreads();
    if (wave == 0) {
        float t1 = red1[lane] + red1[64 + lane] + red1[128 + lane] + red1[192 + lane];
        float t2 = red2[lane] + red2[64 + lane] + red2[128 + lane] + red2[192 + lane];
        atomicAdd(&stats[lane], t1);
        atomicAdd(&stats[64 + lane], t2);
    }
}

// BN (training stats) + ReLU in place; pool accumulation via LDS (batch sorted ->
// a 32-node block spans few graphs), flush once per (graph,feat) per block.
__global__ __launch_bounds__(256) void bn_kernel(
    float* __restrict__ h, const float* __restrict__ stats,
    const float* __restrict__ g, const float* __restrict__ b,
    const int* __restrict__ batch, float* __restrict__ pool,
    int colbase, int n) {
    __shared__ float pl[BN_SPAN][64];
    __shared__ int gmin_s, span_s;
    int tid = threadIdx.x;
    int j = tid & 63;
    int sub = tid >> 6;
    int nbase = blockIdx.x * BN_NODES;
    if (nbase >= n) return;

    if (tid == 0) {
        int last = min(nbase + BN_NODES, n) - 1;
        gmin_s = batch[nbase];
        span_s = batch[last] - gmin_s + 1;
    }
    __syncthreads();
    int gmin = gmin_s, span = span_s;
    bool use_lds = (span <= BN_SPAN);
    if (use_lds) {
        for (int t = tid; t < span * 64; t += 256) ((float*)pl)[t] = 0.0f;
    }
    __syncthreads();

    float invn = 1.0f / (float)n;
    float mu = stats[j] * invn;
    float var = stats[64 + j] * invn - mu * mu;
    float sc = rsqrtf(var + 1e-5f) * g[j];
    float bb = b[j];

    for (int r = sub; r < BN_NODES; r += 4) {
        int i = nbase + r;
        if (i >= n) break;
        size_t idx = (size_t)i * NFEAT + j;
        float v = fmaxf((h[idx] - mu) * sc + bb, 0.0f);
        h[idx] = v;
        int gi = batch[i];
        if (use_lds) atomicAdd(&pl[gi - gmin][j], v);
        else atomicAdd(&pool[(size_t)gi * NCAT + colbase + j], v);
    }
    __syncthreads();
    if (use_lds) {
        for (int t = tid; t < span * 64; t += 256) {
            int s = t >> 6, j2 = t & 63;
            float v = pl[s][j2];
            if (v != 0.0f) atomicAdd(&pool[(size_t)(gmin + s) * NCAT + colbase + j2], v);
        }
    }
}

__global__ void final_kernel(const float* __restrict__ pool, const float* __restrict__ cnt,
                             float* __restrict__ out, int total) {
    int t = blockIdx.x * blockDim.x + threadIdx.x;
    if (t >= total) return;
    int gidx = t / NCAT;
    out[t] = pool[t] / fmaxf(cnt[gidx], 1.0f);
}

extern "C" void kernel_launch(void* const* d_in, const int* in_sizes, int n_in,
                              void* d_out, int out_size, void* d_ws, size_t ws_size,
                              hipStream_t stream) {
    const float* x = (const float*)d_in[0];
    const int* ei = (const int*)d_in[1];
    const int* batch = (const int*)d_in[2];

    const float* Wl[3], *bl[3], *Wr[3], *gm[3], *bt[3];
    for (int L = 0; L < 3; ++L) {
        Wl[L] = (const float*)d_in[3 + 5 * L + 0];
        bl[L] = (const float*)d_in[3 + 5 * L + 1];
        Wr[L] = (const float*)d_in[3 + 5 * L + 2];
        gm[L] = (const float*)d_in[3 + 5 * L + 3];
        bt[L] = (const float*)d_in[3 + 5 * L + 4];
    }

    const int n = in_sizes[0] / NFEAT;
    const int ne = in_sizes[1] / 2;
    const int ngraphs = out_size / NCAT;
    const int* src = ei;
    const int* dstp = ei + ne;

    char* wsb = (char*)d_ws;
    size_t off = 0;
    float* bufA = (float*)(wsb + off); off += (size_t)n * NFEAT * 4;
    float* bufB = (float*)(wsb + off); off += (size_t)n * NFEAT * 4;
    int* csr_src = (int*)(wsb + off);  off += (size_t)ne * 4;
    int* row_start = (int*)(wsb + off); off += (size_t)n * 4;
    int* cursor = (int*)(wsb + off);   off += (size_t)n * 4;
    int* deg = (int*)(wsb + off);      off += (size_t)n * 4;
    float* recip = (float*)(wsb + off); off += (size_t)n * 4;
    float* stats = (float*)(wsb + off); off += 128 * 4;
    float* pool = (float*)(wsb + off);  off += (size_t)ngraphs * NCAT * 4;
    float* cntf = (float*)(wsb + off);  off += (size_t)ngraphs * 4;

    hipMemsetAsync(deg, 0, (size_t)n * sizeof(int), stream);
    hipMemsetAsync(cntf, 0, (size_t)ngraphs * sizeof(float), stream);
    hipMemsetAsync(pool, 0, (size_t)ngraphs * NCAT * sizeof(float), stream);

    deg_kernel<<<(ne + 255) / 256, 256, 0, stream>>>(dstp, deg, ne);
    cnt_kernel<<<(n + 255) / 256, 256, 0, stream>>>(batch, cntf, n);
    recip_kernel<<<(n + 255) / 256, 256, 0, stream>>>(deg, recip, n);
    scan_kernel<<<1, 1024, 0, stream>>>(deg, row_start, cursor, n);
    fill_kernel<<<(ne + 255) / 256, 256, 0, stream>>>(src, dstp, cursor, csr_src, ne);

    const float* lin_in = x;
    float* lout[3] = {bufA, bufB, bufA};
    for (int L = 0; L < 3; ++L) {
        float* dbuf = lout[L];
        hipMemsetAsync(stats, 0, 128 * sizeof(float), stream);
        gatherlin_kernel<<<2048, 256, 0, stream>>>(lin_in, row_start, deg, recip, csr_src,
                                                   Wl[L], bl[L], Wr[L], dbuf, stats, n);
        bn_kernel<<<(n + BN_NODES - 1) / BN_NODES, 256, 0, stream>>>(
            dbuf, stats, gm[L], bt[L], batch, pool, L * NFEAT, n);
        lin_in = dbuf;
    }
    final_kernel<<<(out_size + 255) / 256, 256, 0, stream>>>(pool, cntf, (float*)d_out, out_size);
}